// Round 5
// baseline (848.546 us; speedup 1.0000x reference)
//
#include <hip/hip_runtime.h>
#include <hip/hip_cooperative_groups.h>

namespace cg = cooperative_groups;

#define N_ATOMS 50000
#define N_BONDS 100000
#define BATCH   16
#define N3      150000   // N_ATOMS*3

#define SCAN_BLOCKS ((N_ATOMS + 255) / 256)   // 196

// ---- fast-path workspace layout (4-byte element offsets) ----
#define X_OFF    0            // 4096 floats
#define MC_OFF   4096         // 16 floats (M 9, c 3)
#define DEGI_OFF 4112         // 50000 ints
#define OFFS_OFF 54112        // 50001 ints (+pad to 50016)
#define CUR_OFF  104128       // 50000 ints
#define PART_OFF 154128       // 256 ints
#define DONE_OFF 154384       // 16 ints
#define ADJ_OFF  154400       // 200000 ints
#define HA_OFF   354400       // 2,400,000 floats
#define HB_OFF   2754400      // 2,400,000 floats
#define WS_FAST_BYTES ((size_t)(HB_OFF + 2400000) * 4)

// ---- fallback layout ----
#define DEGF_OFF 4112         // 50000 floats
#define HT_OFF   54144        // 2,400,000 floats
#define NB_OFF   2454144      // 2,400,000 floats (optional in ws)

// ================= shared device helpers =================

// tiny MLP for batch b; all 256 threads of the block participate.
__device__ __forceinline__ void mlp_block(int b, int j,
    const float* __restrict__ alpha,
    const float* __restrict__ w_in, const float* __restrict__ b_in,
    const float* __restrict__ w1a, const float* __restrict__ b1a,
    const float* __restrict__ w1b, const float* __restrict__ b1b,
    const float* __restrict__ w2a, const float* __restrict__ b2a,
    const float* __restrict__ w2b, const float* __restrict__ b2b,
    float* xs, float* ts, float* __restrict__ x_out)
{
    float v = fmaxf(w_in[j] * alpha[b] + b_in[j], 0.f);
    xs[j] = v;
    __syncthreads();

    float acc = b1a[j];
    const float4* wr = reinterpret_cast<const float4*>(w1a + j * 256);
    #pragma unroll 8
    for (int k4 = 0; k4 < 64; ++k4) {
        float4 w = wr[k4];
        acc += w.x * xs[4*k4] + w.y * xs[4*k4+1] + w.z * xs[4*k4+2] + w.w * xs[4*k4+3];
    }
    ts[j] = fmaxf(acc, 0.f);
    __syncthreads();

    acc = b1b[j] + xs[j];
    wr = reinterpret_cast<const float4*>(w1b + j * 256);
    #pragma unroll 8
    for (int k4 = 0; k4 < 64; ++k4) {
        float4 w = wr[k4];
        acc += w.x * ts[4*k4] + w.y * ts[4*k4+1] + w.z * ts[4*k4+2] + w.w * ts[4*k4+3];
    }
    v = fmaxf(acc, 0.f);
    __syncthreads();
    xs[j] = v;
    __syncthreads();

    acc = b2a[j];
    wr = reinterpret_cast<const float4*>(w2a + j * 256);
    #pragma unroll 8
    for (int k4 = 0; k4 < 64; ++k4) {
        float4 w = wr[k4];
        acc += w.x * xs[4*k4] + w.y * xs[4*k4+1] + w.z * xs[4*k4+2] + w.w * xs[4*k4+3];
    }
    ts[j] = fmaxf(acc, 0.f);
    __syncthreads();

    acc = b2b[j] + xs[j];
    wr = reinterpret_cast<const float4*>(w2b + j * 256);
    #pragma unroll 8
    for (int k4 = 0; k4 < 64; ++k4) {
        float4 w = wr[k4];
        acc += w.x * ts[4*k4] + w.y * ts[4*k4+1] + w.z * ts[4*k4+2] + w.w * ts[4*k4+3];
    }
    x_out[b * 256 + j] = fmaxf(acc, 0.f);
}

// fused gather + mean + affine + residual: h_out = h_in + M*mean_nb(h_in)+c
__device__ __forceinline__ void gather_phase(
    const int* __restrict__ offs, const int* __restrict__ adj,
    const float* __restrict__ mc, const float* __restrict__ upd_b,
    const float* __restrict__ h_in, float* __restrict__ h_out,
    int i0, int stride)
{
    for (int t = i0; t < N_ATOMS * BATCH; t += stride) {
        int n = t >> 4, b = t & 15;
        int o0 = offs[n], o1 = offs[n + 1];
        int base = n * 48 + b * 3;
        float d0, d1, d2;
        if (o1 > o0) {
            float s0 = 0.f, s1 = 0.f, s2 = 0.f;
            for (int j = o0; j < o1; ++j) {
                const float* hs = h_in + adj[j] * 48 + b * 3;
                s0 += hs[0]; s1 += hs[1]; s2 += hs[2];
            }
            float inv = 1.f / (float)(o1 - o0);
            s0 *= inv; s1 *= inv; s2 *= inv;
            d0 = mc[9]  + mc[0]*s0 + mc[1]*s1 + mc[2]*s2;
            d1 = mc[10] + mc[3]*s0 + mc[4]*s1 + mc[5]*s2;
            d2 = mc[11] + mc[6]*s0 + mc[7]*s1 + mc[8]*s2;
        } else {
            d0 = upd_b[0]; d1 = upd_b[1]; d2 = upd_b[2];
        }
        h_out[base]     = h_in[base]     + d0;
        h_out[base + 1] = h_in[base + 1] + d1;
        h_out[base + 2] = h_in[base + 2] + d2;
    }
}

// ================= one cooperative kernel for everything except the GEMM =================
struct CoopParams {
    const float *alpha, *pos;
    const int   *bonds;
    const float *w_in, *b_in, *w1a, *b1a, *w1b, *b1b, *w2a, *b2a, *w2b, *b2b;
    const float *msg_w, *msg_b, *upd_w, *upd_b;
    float *x, *mc;
    int *deg, *offs, *cursor, *part, *done, *adj;
    float *hA, *hB;
};

__global__ __launch_bounds__(256) void coop_kernel(CoopParams p)
{
    cg::grid_group grid = cg::this_grid();
    __shared__ float smem[512];
    float* xs = smem;
    float* ts = smem + 256;
    int*   sh = (int*)smem;          // 512 int slots; [256] used as a flag
    const int bid = blockIdx.x, tid = threadIdx.x;
    const int nb  = gridDim.x;
    const int gtid = bid * 256 + tid, gstride = nb * 256;

    // ---------- P0: MLP (blocks 0-15) | mc + counter reset (block 16) |
    //            transpose h + zero deg (blocks 17+) ----------
    if (bid < 16) {
        mlp_block(bid, tid, p.alpha, p.w_in, p.b_in,
                  p.w1a, p.b1a, p.w1b, p.b1b, p.w2a, p.b2a, p.w2b, p.b2b,
                  xs, ts, p.x);
    } else if (bid == 16) {
        if (tid < 9) {
            int d = tid / 3, dp = tid % 3;
            float s = 0.f;
            for (int k = 0; k < 128; ++k) s += p.upd_w[d*128 + k] * p.msg_w[k*3 + dp];
            p.mc[tid] = s;
        } else if (tid < 12) {
            int d = tid - 9;
            float s = p.upd_b[d];
            for (int k = 0; k < 128; ++k) s += p.upd_w[d*128 + k] * p.msg_b[k];
            p.mc[9 + d] = s;
        }
        if (tid == 63) *p.done = 0;
    } else {
        int i0 = (bid - 17) * 256 + tid;
        int st = (nb - 17) * 256;
        for (int i = i0; i < N_ATOMS / 4; i += st)
            ((int4*)p.deg)[i] = make_int4(0, 0, 0, 0);
        for (int i = i0; i < N_ATOMS * 48; i += st) {
            int n = i / 48, c = i - n * 48;
            int b = c / 3, d = c - b * 3;
            p.hA[i] = p.pos[(b * N_ATOMS + n) * 3 + d];
        }
    }
    grid.sync();

    // ---------- P1: degree count ----------
    for (int e = gtid; e < N_BONDS; e += gstride) {
        atomicAdd(p.deg + p.bonds[2*e],     1);
        atomicAdd(p.deg + p.bonds[2*e + 1], 1);
    }
    grid.sync();

    // ---------- P2: per-tile reduce; last finishing block scans partials ----------
    if (bid < SCAN_BLOCKS) {
        int idx = gtid;
        sh[tid] = (idx < N_ATOMS) ? p.deg[idx] : 0;
        __syncthreads();
        #pragma unroll
        for (int s = 128; s > 0; s >>= 1) {
            if (tid < s) sh[tid] += sh[tid + s];
            __syncthreads();
        }
        if (tid == 0) {
            p.part[bid] = sh[0];
            __threadfence();
            int old = atomicAdd(p.done, 1);
            __threadfence();
            sh[256] = (old == SCAN_BLOCKS - 1) ? 1 : 0;
        }
        __syncthreads();
        if (sh[256]) {      // this block saw all partials written: do the top scan
            int pv = (tid < SCAN_BLOCKS) ? p.part[tid] : 0;
            sh[tid] = pv;
            __syncthreads();
            #pragma unroll
            for (int off = 1; off < 256; off <<= 1) {
                int t = sh[tid];
                int a = (tid >= off) ? sh[tid - off] : 0;
                __syncthreads();
                sh[tid] = t + a;
                __syncthreads();
            }
            if (tid < SCAN_BLOCKS) p.part[tid] = sh[tid] - pv;   // exclusive
        }
    }
    grid.sync();

    // ---------- P3: emit offs / cursor ----------
    if (bid < SCAN_BLOCKS) {
        int idx = gtid;
        int v = (idx < N_ATOMS) ? p.deg[idx] : 0;
        sh[tid] = v;
        __syncthreads();
        #pragma unroll
        for (int off = 1; off < 256; off <<= 1) {
            int t = sh[tid];
            int a = (tid >= off) ? sh[tid - off] : 0;
            __syncthreads();
            sh[tid] = t + a;
            __syncthreads();
        }
        int excl = sh[tid] - v + p.part[bid];
        if (idx < N_ATOMS) { p.offs[idx] = excl; p.cursor[idx] = excl; }
        if (idx == N_ATOMS - 1) p.offs[N_ATOMS] = 2 * N_BONDS;
    }
    grid.sync();

    // ---------- P4: CSR fill ----------
    for (int e = gtid; e < N_BONDS; e += gstride) {
        int a = p.bonds[2*e], b = p.bonds[2*e + 1];
        p.adj[atomicAdd(p.cursor + b, 1)] = a;
        p.adj[atomicAdd(p.cursor + a, 1)] = b;
    }
    grid.sync();

    // ---------- P5/P6: two graph iterations ----------
    gather_phase(p.offs, p.adj, p.mc, p.upd_b, p.hA, p.hB, gtid, gstride);
    grid.sync();
    gather_phase(p.offs, p.adj, p.mc, p.upd_b, p.hB, p.hA, gtid, gstride);
}

// ---------------- fused output: standard GEMM + b_out + go-affine(h) ----------------
// 1 wave per block; each thread computes 2 rows x 16 batches.
__global__ __launch_bounds__(64) void out_kernel(
    const float* __restrict__ w_out, const float* __restrict__ b_out,
    const float* __restrict__ x, const float* __restrict__ h_t,
    const float* __restrict__ go_w, const float* __restrict__ go_b,
    float* __restrict__ out)
{
    __shared__ float4 xs[1024];                 // [b][k4], 16 KiB
    const int tid = threadIdx.x;
    const float4* xv = reinterpret_cast<const float4*>(x);
    #pragma unroll
    for (int i = 0; i < 16; ++i) xs[tid + i * 64] = xv[tid + i * 64];
    __syncthreads();

    const int r0 = blockIdx.x * 128 + tid;
    const int r1 = r0 + 64;
    const bool v1 = (r1 < N3);
    const int r1c = v1 ? r1 : r0;

    const float4* wr0 = reinterpret_cast<const float4*>(w_out + (size_t)r0 * 256);
    const float4* wr1 = reinterpret_cast<const float4*>(w_out + (size_t)r1c * 256);

    float acc0[16], acc1[16];
    #pragma unroll
    for (int b = 0; b < 16; ++b) { acc0[b] = 0.f; acc1[b] = 0.f; }

    float4 wbuf0[4], wbuf1[4];
    #pragma unroll
    for (int i = 0; i < 4; ++i) { wbuf0[i] = wr0[i]; wbuf1[i] = wr1[i]; }

    #pragma unroll 1
    for (int c = 0; c < 16; ++c) {
        float4 wc0[4], wc1[4];
        #pragma unroll
        for (int i = 0; i < 4; ++i) { wc0[i] = wbuf0[i]; wc1[i] = wbuf1[i]; }
        if (c < 15) {
            #pragma unroll
            for (int i = 0; i < 4; ++i) {
                wbuf0[i] = wr0[(c + 1) * 4 + i];
                wbuf1[i] = wr1[(c + 1) * 4 + i];
            }
        }
        #pragma unroll
        for (int i = 0; i < 4; ++i) {
            const int k4 = c * 4 + i;
            #pragma unroll
            for (int b = 0; b < 16; ++b) {
                float4 xf = xs[b * 64 + k4];
                acc0[b] += wc0[i].x * xf.x + wc0[i].y * xf.y
                         + wc0[i].z * xf.z + wc0[i].w * xf.w;
                acc1[b] += wc1[i].x * xf.x + wc1[i].y * xf.y
                         + wc1[i].z * xf.z + wc1[i].w * xf.w;
            }
        }
    }

    {
        const int n = r0 / 3, d = r0 - 3 * n;
        const float g0 = go_w[d*3], g1 = go_w[d*3 + 1], g2 = go_w[d*3 + 2];
        const float gb = go_b[d] + b_out[r0];
        const float* hb = h_t + n * 48;
        #pragma unroll
        for (int b = 0; b < 16; ++b) {
            float g = gb + g0 * hb[b*3] + g1 * hb[b*3 + 1] + g2 * hb[b*3 + 2];
            out[b * N3 + r0] = acc0[b] + g;
        }
    }
    if (v1) {
        const int n = r1 / 3, d = r1 - 3 * n;
        const float g0 = go_w[d*3], g1 = go_w[d*3 + 1], g2 = go_w[d*3 + 2];
        const float gb = go_b[d] + b_out[r1];
        const float* hb = h_t + n * 48;
        #pragma unroll
        for (int b = 0; b < 16; ++b) {
            float g = gb + g0 * hb[b*3] + g1 * hb[b*3 + 1] + g2 * hb[b*3 + 2];
            out[b * N3 + r1] = acc1[b] + g;
        }
    }
}

// ================= fallback (small-ws) kernels: atomic scatter path =================
__global__ void zero4_kernel(int4* __restrict__ p, int n4)
{
    int t = blockIdx.x * 256 + threadIdx.x;
    if (t < n4) p[t] = make_int4(0, 0, 0, 0);
}

__global__ void mlp_head_kernel(const float* __restrict__ alpha,
    const float* __restrict__ w_in, const float* __restrict__ b_in,
    const float* __restrict__ w1a, const float* __restrict__ b1a,
    const float* __restrict__ w1b, const float* __restrict__ b1b,
    const float* __restrict__ w2a, const float* __restrict__ b2a,
    const float* __restrict__ w2b, const float* __restrict__ b2b,
    const float* __restrict__ msg_w, const float* __restrict__ msg_b,
    const float* __restrict__ upd_w, const float* __restrict__ upd_b,
    float* __restrict__ x_out, float* __restrict__ mc)
{
    const int b = blockIdx.x, j = threadIdx.x;
    if (b == 16) {
        if (j < 9) {
            int d = j / 3, dp = j % 3;
            float s = 0.f;
            for (int k = 0; k < 128; ++k) s += upd_w[d*128 + k] * msg_w[k*3 + dp];
            mc[j] = s;
        } else if (j < 12) {
            int d = j - 9;
            float s = upd_b[d];
            for (int k = 0; k < 128; ++k) s += upd_w[d*128 + k] * msg_b[k];
            mc[9 + d] = s;
        }
        return;
    }
    __shared__ float xs[256];
    __shared__ float ts[256];
    mlp_block(b, j, alpha, w_in, b_in, w1a, b1a, w1b, b1b, w2a, b2a, w2b, b2b,
              xs, ts, x_out);
}

__global__ void transpose_in_kernel(const float* __restrict__ pos, float* __restrict__ h_t)
{
    int t = blockIdx.x * blockDim.x + threadIdx.x;
    if (t >= N_ATOMS * 48) return;
    int n = t / 48, c = t % 48;
    int b = c / 3, d = c % 3;
    h_t[t] = pos[(b * N_ATOMS + n) * 3 + d];
}

__global__ void degf_kernel(const int* __restrict__ bonds, float* __restrict__ deg)
{
    int e = blockIdx.x * blockDim.x + threadIdx.x;
    if (e >= N_BONDS) return;
    atomicAdd(deg + bonds[2*e],     1.f);
    atomicAdd(deg + bonds[2*e + 1], 1.f);
}

__global__ void scatter_kernel(const int* __restrict__ bonds,
                               const float* __restrict__ h_t, float* __restrict__ nb_t)
{
    int t = blockIdx.x * 192 + threadIdx.x;
    int e = t / 48, c = t % 48;
    if (e >= N_BONDS) return;
    int a  = bonds[2*e];
    int bb = bonds[2*e + 1];
    float va = h_t[a  * 48 + c];
    float vb = h_t[bb * 48 + c];
    atomicAdd(nb_t + bb * 48 + c, va);
    atomicAdd(nb_t + a  * 48 + c, vb);
}

__global__ void update_kernel(const float* __restrict__ nb_t, const float* __restrict__ deg,
                              const float* __restrict__ mc, const float* __restrict__ upd_b,
                              float* __restrict__ h_t)
{
    int t = blockIdx.x * blockDim.x + threadIdx.x;
    if (t >= N_ATOMS * BATCH) return;
    int n = t >> 4;
    int base = n * 48 + (t & 15) * 3;
    float dg = deg[n];
    float d0, d1, d2;
    if (dg > 0.f) {
        float inv = 1.f / dg;
        float m0 = nb_t[base] * inv, m1 = nb_t[base+1] * inv, m2 = nb_t[base+2] * inv;
        d0 = mc[9]  + mc[0]*m0 + mc[1]*m1 + mc[2]*m2;
        d1 = mc[10] + mc[3]*m0 + mc[4]*m1 + mc[5]*m2;
        d2 = mc[11] + mc[6]*m0 + mc[7]*m1 + mc[8]*m2;
    } else {
        d0 = upd_b[0]; d1 = upd_b[1]; d2 = upd_b[2];
    }
    h_t[base]     += d0;
    h_t[base + 1] += d1;
    h_t[base + 2] += d2;
}

extern "C" void kernel_launch(void* const* d_in, const int* in_sizes, int n_in,
                              void* d_out, int out_size, void* d_ws, size_t ws_size,
                              hipStream_t stream)
{
    const float* alpha = (const float*)d_in[0];
    const float* pos   = (const float*)d_in[1];
    const int*   bonds = (const int*)  d_in[2];
    const float* w_in  = (const float*)d_in[3];
    const float* b_in  = (const float*)d_in[4];
    const float* w1a   = (const float*)d_in[5];
    const float* b1a   = (const float*)d_in[6];
    const float* w1b   = (const float*)d_in[7];
    const float* b1b   = (const float*)d_in[8];
    const float* w2a   = (const float*)d_in[9];
    const float* b2a   = (const float*)d_in[10];
    const float* w2b   = (const float*)d_in[11];
    const float* b2b   = (const float*)d_in[12];
    const float* w_out = (const float*)d_in[13];
    const float* b_out = (const float*)d_in[14];
    const float* msg_w = (const float*)d_in[15];
    const float* msg_b = (const float*)d_in[16];
    const float* upd_w = (const float*)d_in[17];
    const float* upd_b = (const float*)d_in[18];
    const float* go_w  = (const float*)d_in[19];
    const float* go_b  = (const float*)d_in[20];

    float* out = (float*)d_out;
    float* ws  = (float*)d_ws;
    float* x   = ws + X_OFF;
    float* mc  = ws + MC_OFF;

    float* h_final;
    if (ws_size >= WS_FAST_BYTES) {
        // -------- single cooperative dispatch for MLP + CSR + 2 graph iters --------
        CoopParams cp;
        cp.alpha = alpha; cp.pos = pos; cp.bonds = bonds;
        cp.w_in = w_in; cp.b_in = b_in;
        cp.w1a = w1a; cp.b1a = b1a; cp.w1b = w1b; cp.b1b = b1b;
        cp.w2a = w2a; cp.b2a = b2a; cp.w2b = w2b; cp.b2b = b2b;
        cp.msg_w = msg_w; cp.msg_b = msg_b; cp.upd_w = upd_w; cp.upd_b = upd_b;
        cp.x = x; cp.mc = mc;
        cp.deg    = (int*)(ws + DEGI_OFF);
        cp.offs   = (int*)(ws + OFFS_OFF);
        cp.cursor = (int*)(ws + CUR_OFF);
        cp.part   = (int*)(ws + PART_OFF);
        cp.done   = (int*)(ws + DONE_OFF);
        cp.adj    = (int*)(ws + ADJ_OFF);
        cp.hA     = ws + HA_OFF;
        cp.hB     = ws + HB_OFF;

        int maxB = 0;
        if (hipOccupancyMaxActiveBlocksPerMultiprocessor(&maxB, coop_kernel, 256, 0) != hipSuccess
            || maxB < 1)
            maxB = 2;                       // conservative: 2 blocks/CU always fits
        int grid = maxB * 256;              // 256 CUs on MI355X
        if (grid > 1024) grid = 1024;       // cap: barrier cost grows with grid
        if (grid < 256)  grid = 256;        // need >= 213 blocks for phase mapping

        void* kargs[] = { (void*)&cp };
        hipLaunchCooperativeKernel(reinterpret_cast<const void*>(&coop_kernel),
                                   dim3(grid), dim3(256), kargs, 0, stream);
        h_final = cp.hA;
    } else {
        // -------- fallback: multi-dispatch atomic scatter path --------
        float* degf = ws + DEGF_OFF;
        float* h_t  = ws + HT_OFF;
        size_t need_full = (size_t)(NB_OFF + N_ATOMS * 48) * sizeof(float);
        float* nb_t = (ws_size >= need_full) ? (ws + NB_OFF) : out;

        mlp_head_kernel<<<17, 256, 0, stream>>>(alpha, w_in, b_in,
                                                w1a, b1a, w1b, b1b,
                                                w2a, b2a, w2b, b2b,
                                                msg_w, msg_b, upd_w, upd_b, x, mc);
        zero4_kernel<<<(N_ATOMS / 4 + 255) / 256, 256, 0, stream>>>((int4*)degf, N_ATOMS / 4);
        degf_kernel<<<(N_BONDS + 255) / 256, 256, 0, stream>>>(bonds, degf);
        transpose_in_kernel<<<(N_ATOMS * 48 + 255) / 256, 256, 0, stream>>>(pos, h_t);
        for (int it = 0; it < 2; ++it) {
            zero4_kernel<<<(N_ATOMS * 48 / 4 + 255) / 256, 256, 0, stream>>>((int4*)nb_t, N_ATOMS * 48 / 4);
            scatter_kernel<<<25000, 192, 0, stream>>>(bonds, h_t, nb_t);
            update_kernel<<<(N_ATOMS * BATCH + 255) / 256, 256, 0, stream>>>(nb_t, degf, mc, upd_b, h_t);
        }
        h_final = h_t;
    }

    out_kernel<<<(N3 + 127) / 128, 64, 0, stream>>>(w_out, b_out, x, h_final, go_w, go_b, out);
}

// Round 6
// 347.066 us; speedup vs baseline: 2.4449x; 2.4449x over previous
//
#include <hip/hip_runtime.h>

#define N_ATOMS 50000
#define N_BONDS 100000
#define BATCH   16
#define N3      150000   // N_ATOMS*3
#define BK      32       // bucket capacity per atom (Poisson(4) => P(deg>32) ~ 1e-15)

#define GRAPH_GRID 512   // 2 blocks/CU on 256 CUs -> co-residency guaranteed w/ launch_bounds

// ---- fast-path workspace layout (4-byte element offsets) ----
#define X_OFF    0            // 4096 floats
#define MC_OFF   4096         // 16 floats (M 9, c 3)
#define BAR_OFF  4112         // 8 ints (ctr0, flag0, ctr1, flag1, pad)
#define CNT_OFF  4120         // 50000 ints (16B-aligned: 4120*4 % 16 == 0)
#define BKT_OFF  54120        // 50000*32 = 1,600,000 ints
#define HA_OFF   1654120      // 2,400,000 floats
#define HB_OFF   4054120      // 2,400,000 floats
#define WS_FAST_BYTES ((size_t)(HB_OFF + 2400000) * 4)   // ~25.8 MB

// ---- fallback layout ----
#define DEGF_OFF 4112         // 50000 floats
#define HT_OFF   54144        // 2,400,000 floats
#define NB_OFF   2454144      // 2,400,000 floats (optional in ws)

// ================= shared device helpers =================

// tiny MLP for batch b; all 256 threads of the block participate.
__device__ __forceinline__ void mlp_block(int b, int j,
    const float* __restrict__ alpha,
    const float* __restrict__ w_in, const float* __restrict__ b_in,
    const float* __restrict__ w1a, const float* __restrict__ b1a,
    const float* __restrict__ w1b, const float* __restrict__ b1b,
    const float* __restrict__ w2a, const float* __restrict__ b2a,
    const float* __restrict__ w2b, const float* __restrict__ b2b,
    float* xs, float* ts, float* __restrict__ x_out)
{
    float v = fmaxf(w_in[j] * alpha[b] + b_in[j], 0.f);
    xs[j] = v;
    __syncthreads();

    float acc = b1a[j];
    const float4* wr = reinterpret_cast<const float4*>(w1a + j * 256);
    #pragma unroll 8
    for (int k4 = 0; k4 < 64; ++k4) {
        float4 w = wr[k4];
        acc += w.x * xs[4*k4] + w.y * xs[4*k4+1] + w.z * xs[4*k4+2] + w.w * xs[4*k4+3];
    }
    ts[j] = fmaxf(acc, 0.f);
    __syncthreads();

    acc = b1b[j] + xs[j];
    wr = reinterpret_cast<const float4*>(w1b + j * 256);
    #pragma unroll 8
    for (int k4 = 0; k4 < 64; ++k4) {
        float4 w = wr[k4];
        acc += w.x * ts[4*k4] + w.y * ts[4*k4+1] + w.z * ts[4*k4+2] + w.w * ts[4*k4+3];
    }
    v = fmaxf(acc, 0.f);
    __syncthreads();
    xs[j] = v;
    __syncthreads();

    acc = b2a[j];
    wr = reinterpret_cast<const float4*>(w2a + j * 256);
    #pragma unroll 8
    for (int k4 = 0; k4 < 64; ++k4) {
        float4 w = wr[k4];
        acc += w.x * xs[4*k4] + w.y * xs[4*k4+1] + w.z * xs[4*k4+2] + w.w * xs[4*k4+3];
    }
    ts[j] = fmaxf(acc, 0.f);
    __syncthreads();

    acc = b2b[j] + xs[j];
    wr = reinterpret_cast<const float4*>(w2b + j * 256);
    #pragma unroll 8
    for (int k4 = 0; k4 < 64; ++k4) {
        float4 w = wr[k4];
        acc += w.x * ts[4*k4] + w.y * ts[4*k4+1] + w.z * ts[4*k4+2] + w.w * ts[4*k4+3];
    }
    x_out[b * 256 + j] = fmaxf(acc, 0.f);
}

// bucket gather + mean + affine + residual: h_out = h_in + M*mean_nb(h_in)+c
__device__ __forceinline__ void gather_phase(
    const int* __restrict__ cnt, const int* __restrict__ bucket,
    const float* __restrict__ mc, const float* __restrict__ upd_b,
    const float* __restrict__ h_in, float* __restrict__ h_out,
    int i0, int stride)
{
    for (int t = i0; t < N_ATOMS * BATCH; t += stride) {
        int n = t >> 4, b = t & 15;
        int dg = cnt[n];
        int base = n * 48 + b * 3;
        float d0, d1, d2;
        if (dg > 0) {
            int m = dg > BK ? BK : dg;
            float s0 = 0.f, s1 = 0.f, s2 = 0.f;
            const int* bk = bucket + n * BK;
            for (int j = 0; j < m; ++j) {
                const float* hs = h_in + bk[j] * 48 + b * 3;
                s0 += hs[0]; s1 += hs[1]; s2 += hs[2];
            }
            float inv = 1.f / (float)dg;
            s0 *= inv; s1 *= inv; s2 *= inv;
            d0 = mc[9]  + mc[0]*s0 + mc[1]*s1 + mc[2]*s2;
            d1 = mc[10] + mc[3]*s0 + mc[4]*s1 + mc[5]*s2;
            d2 = mc[11] + mc[6]*s0 + mc[7]*s1 + mc[8]*s2;
        } else {
            d0 = upd_b[0]; d1 = upd_b[1]; d2 = upd_b[2];
        }
        h_out[base]     = h_in[base]     + d0;
        h_out[base + 1] = h_in[base + 1] + d1;
        h_out[base + 2] = h_in[base + 2] + d2;
    }
}

// ================= K1: prep (MLP + mc + transpose + cnt-zero + barrier-init) =================
struct PrepParams {
    const float *alpha, *pos;
    const float *w_in, *b_in, *w1a, *b1a, *w1b, *b1b, *w2a, *b2a, *w2b, *b2b;
    const float *msg_w, *msg_b, *upd_w, *upd_b;
    float *x, *mc;
    int *bar, *cnt;
    float *hA;
};

__global__ __launch_bounds__(256) void prep_kernel(PrepParams p)
{
    __shared__ float smem[512];
    const int bid = blockIdx.x, tid = threadIdx.x;
    const int nb = gridDim.x;

    if (bid < 16) {
        mlp_block(bid, tid, p.alpha, p.w_in, p.b_in,
                  p.w1a, p.b1a, p.w1b, p.b1b, p.w2a, p.b2a, p.w2b, p.b2b,
                  smem, smem + 256, p.x);
    } else if (bid == 16) {
        if (tid < 9) {
            int d = tid / 3, dp = tid % 3;
            float s = 0.f;
            for (int k = 0; k < 128; ++k) s += p.upd_w[d*128 + k] * p.msg_w[k*3 + dp];
            p.mc[tid] = s;
        } else if (tid < 12) {
            int d = tid - 9;
            float s = p.upd_b[d];
            for (int k = 0; k < 128; ++k) s += p.upd_w[d*128 + k] * p.msg_b[k];
            p.mc[9 + d] = s;
        } else if (tid >= 16 && tid < 24) {
            p.bar[tid - 16] = 0;                 // barrier counters/flags
        }
    } else {
        const int i0 = (bid - 17) * 256 + tid;
        const int st = (nb - 17) * 256;
        if (i0 < N_ATOMS / 4)
            ((int4*)p.cnt)[i0] = make_int4(0, 0, 0, 0);
        for (int i = i0; i < N_ATOMS * 48; i += st) {
            int n = i / 48, c = i - n * 48;
            int b = c / 3, d = c - b * 3;
            p.hA[i] = p.pos[(b * N_ATOMS + n) * 3 + d];
        }
    }
}

// ================= K2: graph (bucket fill -> bar -> gather1 -> bar -> gather2) =================
struct GraphParams {
    const int *bonds;
    const float *mc, *upd_b;
    int *cnt, *bucket, *bar;
    float *hA, *hB;
};

__device__ __forceinline__ void dev_barrier(int* ctr, int* flag)
{
    __syncthreads();
    if (threadIdx.x == 0) {
        __threadfence();   // release: make this block's stores visible device-wide
        int arrived = __hip_atomic_fetch_add(ctr, 1, __ATOMIC_ACQ_REL,
                                             __HIP_MEMORY_SCOPE_AGENT);
        if (arrived == GRAPH_GRID - 1) {
            __hip_atomic_store(flag, 1, __ATOMIC_RELEASE, __HIP_MEMORY_SCOPE_AGENT);
        } else {
            while (!__hip_atomic_load(flag, __ATOMIC_ACQUIRE, __HIP_MEMORY_SCOPE_AGENT))
                __builtin_amdgcn_s_sleep(32);
        }
        __threadfence();   // acquire
    }
    __syncthreads();
}

__global__ __launch_bounds__(256, 2) void graph_kernel(GraphParams p)
{
    const int gtid = blockIdx.x * 256 + threadIdx.x;
    const int gstride = GRAPH_GRID * 256;

    // P0: bucket fill + degree count in one pass
    for (int e = gtid; e < N_BONDS; e += gstride) {
        int a = p.bonds[2*e], b = p.bonds[2*e + 1];
        int sa = atomicAdd(p.cnt + a, 1);
        if (sa < BK) p.bucket[a * BK + sa] = b;
        int sb = atomicAdd(p.cnt + b, 1);
        if (sb < BK) p.bucket[b * BK + sb] = a;
    }
    dev_barrier(p.bar + 0, p.bar + 1);

    // P1: graph iteration 1
    gather_phase(p.cnt, p.bucket, p.mc, p.upd_b, p.hA, p.hB, gtid, gstride);
    dev_barrier(p.bar + 2, p.bar + 3);

    // P2: graph iteration 2
    gather_phase(p.cnt, p.bucket, p.mc, p.upd_b, p.hB, p.hA, gtid, gstride);
}

// ---------------- K3: fused output GEMM + b_out + go-affine(h) ----------------
__global__ __launch_bounds__(64) void out_kernel(
    const float* __restrict__ w_out, const float* __restrict__ b_out,
    const float* __restrict__ x, const float* __restrict__ h_t,
    const float* __restrict__ go_w, const float* __restrict__ go_b,
    float* __restrict__ out)
{
    __shared__ float4 xs[1024];                 // [b][k4], 16 KiB
    const int tid = threadIdx.x;
    const float4* xv = reinterpret_cast<const float4*>(x);
    #pragma unroll
    for (int i = 0; i < 16; ++i) xs[tid + i * 64] = xv[tid + i * 64];
    __syncthreads();

    const int r0 = blockIdx.x * 128 + tid;
    const int r1 = r0 + 64;
    const bool v1 = (r1 < N3);
    const int r1c = v1 ? r1 : r0;

    const float4* wr0 = reinterpret_cast<const float4*>(w_out + (size_t)r0 * 256);
    const float4* wr1 = reinterpret_cast<const float4*>(w_out + (size_t)r1c * 256);

    float acc0[16], acc1[16];
    #pragma unroll
    for (int b = 0; b < 16; ++b) { acc0[b] = 0.f; acc1[b] = 0.f; }

    float4 wbuf0[4], wbuf1[4];
    #pragma unroll
    for (int i = 0; i < 4; ++i) { wbuf0[i] = wr0[i]; wbuf1[i] = wr1[i]; }

    #pragma unroll 1
    for (int c = 0; c < 16; ++c) {
        float4 wc0[4], wc1[4];
        #pragma unroll
        for (int i = 0; i < 4; ++i) { wc0[i] = wbuf0[i]; wc1[i] = wbuf1[i]; }
        if (c < 15) {
            #pragma unroll
            for (int i = 0; i < 4; ++i) {
                wbuf0[i] = wr0[(c + 1) * 4 + i];
                wbuf1[i] = wr1[(c + 1) * 4 + i];
            }
        }
        #pragma unroll
        for (int i = 0; i < 4; ++i) {
            const int k4 = c * 4 + i;
            #pragma unroll
            for (int b = 0; b < 16; ++b) {
                float4 xf = xs[b * 64 + k4];
                acc0[b] += wc0[i].x * xf.x + wc0[i].y * xf.y
                         + wc0[i].z * xf.z + wc0[i].w * xf.w;
                acc1[b] += wc1[i].x * xf.x + wc1[i].y * xf.y
                         + wc1[i].z * xf.z + wc1[i].w * xf.w;
            }
        }
    }

    {
        const int n = r0 / 3, d = r0 - 3 * n;
        const float g0 = go_w[d*3], g1 = go_w[d*3 + 1], g2 = go_w[d*3 + 2];
        const float gb = go_b[d] + b_out[r0];
        const float* hb = h_t + n * 48;
        #pragma unroll
        for (int b = 0; b < 16; ++b) {
            float g = gb + g0 * hb[b*3] + g1 * hb[b*3 + 1] + g2 * hb[b*3 + 2];
            out[b * N3 + r0] = acc0[b] + g;
        }
    }
    if (v1) {
        const int n = r1 / 3, d = r1 - 3 * n;
        const float g0 = go_w[d*3], g1 = go_w[d*3 + 1], g2 = go_w[d*3 + 2];
        const float gb = go_b[d] + b_out[r1];
        const float* hb = h_t + n * 48;
        #pragma unroll
        for (int b = 0; b < 16; ++b) {
            float g = gb + g0 * hb[b*3] + g1 * hb[b*3 + 1] + g2 * hb[b*3 + 2];
            out[b * N3 + r1] = acc1[b] + g;
        }
    }
}

// ================= fallback (small-ws) kernels: atomic scatter path =================
__global__ void zero4_kernel(int4* __restrict__ p, int n4)
{
    int t = blockIdx.x * 256 + threadIdx.x;
    if (t < n4) p[t] = make_int4(0, 0, 0, 0);
}

__global__ void mlp_head_kernel(const float* __restrict__ alpha,
    const float* __restrict__ w_in, const float* __restrict__ b_in,
    const float* __restrict__ w1a, const float* __restrict__ b1a,
    const float* __restrict__ w1b, const float* __restrict__ b1b,
    const float* __restrict__ w2a, const float* __restrict__ b2a,
    const float* __restrict__ w2b, const float* __restrict__ b2b,
    const float* __restrict__ msg_w, const float* __restrict__ msg_b,
    const float* __restrict__ upd_w, const float* __restrict__ upd_b,
    float* __restrict__ x_out, float* __restrict__ mc)
{
    const int b = blockIdx.x, j = threadIdx.x;
    if (b == 16) {
        if (j < 9) {
            int d = j / 3, dp = j % 3;
            float s = 0.f;
            for (int k = 0; k < 128; ++k) s += upd_w[d*128 + k] * msg_w[k*3 + dp];
            mc[j] = s;
        } else if (j < 12) {
            int d = j - 9;
            float s = upd_b[d];
            for (int k = 0; k < 128; ++k) s += upd_w[d*128 + k] * msg_b[k];
            mc[9 + d] = s;
        }
        return;
    }
    __shared__ float xs[256];
    __shared__ float ts[256];
    mlp_block(b, j, alpha, w_in, b_in, w1a, b1a, w1b, b1b, w2a, b2a, w2b, b2b,
              xs, ts, x_out);
}

__global__ void transpose_in_kernel(const float* __restrict__ pos, float* __restrict__ h_t)
{
    int t = blockIdx.x * blockDim.x + threadIdx.x;
    if (t >= N_ATOMS * 48) return;
    int n = t / 48, c = t % 48;
    int b = c / 3, d = c % 3;
    h_t[t] = pos[(b * N_ATOMS + n) * 3 + d];
}

__global__ void degf_kernel(const int* __restrict__ bonds, float* __restrict__ deg)
{
    int e = blockIdx.x * blockDim.x + threadIdx.x;
    if (e >= N_BONDS) return;
    atomicAdd(deg + bonds[2*e],     1.f);
    atomicAdd(deg + bonds[2*e + 1], 1.f);
}

__global__ void scatter_kernel(const int* __restrict__ bonds,
                               const float* __restrict__ h_t, float* __restrict__ nb_t)
{
    int t = blockIdx.x * 192 + threadIdx.x;
    int e = t / 48, c = t % 48;
    if (e >= N_BONDS) return;
    int a  = bonds[2*e];
    int bb = bonds[2*e + 1];
    float va = h_t[a  * 48 + c];
    float vb = h_t[bb * 48 + c];
    atomicAdd(nb_t + bb * 48 + c, va);
    atomicAdd(nb_t + a  * 48 + c, vb);
}

__global__ void update_kernel(const float* __restrict__ nb_t, const float* __restrict__ deg,
                              const float* __restrict__ mc, const float* __restrict__ upd_b,
                              float* __restrict__ h_t)
{
    int t = blockIdx.x * blockDim.x + threadIdx.x;
    if (t >= N_ATOMS * BATCH) return;
    int n = t >> 4;
    int base = n * 48 + (t & 15) * 3;
    float dg = deg[n];
    float d0, d1, d2;
    if (dg > 0.f) {
        float inv = 1.f / dg;
        float m0 = nb_t[base] * inv, m1 = nb_t[base+1] * inv, m2 = nb_t[base+2] * inv;
        d0 = mc[9]  + mc[0]*m0 + mc[1]*m1 + mc[2]*m2;
        d1 = mc[10] + mc[3]*m0 + mc[4]*m1 + mc[5]*m2;
        d2 = mc[11] + mc[6]*m0 + mc[7]*m1 + mc[8]*m2;
    } else {
        d0 = upd_b[0]; d1 = upd_b[1]; d2 = upd_b[2];
    }
    h_t[base]     += d0;
    h_t[base + 1] += d1;
    h_t[base + 2] += d2;
}

extern "C" void kernel_launch(void* const* d_in, const int* in_sizes, int n_in,
                              void* d_out, int out_size, void* d_ws, size_t ws_size,
                              hipStream_t stream)
{
    const float* alpha = (const float*)d_in[0];
    const float* pos   = (const float*)d_in[1];
    const int*   bonds = (const int*)  d_in[2];
    const float* w_in  = (const float*)d_in[3];
    const float* b_in  = (const float*)d_in[4];
    const float* w1a   = (const float*)d_in[5];
    const float* b1a   = (const float*)d_in[6];
    const float* w1b   = (const float*)d_in[7];
    const float* b1b   = (const float*)d_in[8];
    const float* w2a   = (const float*)d_in[9];
    const float* b2a   = (const float*)d_in[10];
    const float* w2b   = (const float*)d_in[11];
    const float* b2b   = (const float*)d_in[12];
    const float* w_out = (const float*)d_in[13];
    const float* b_out = (const float*)d_in[14];
    const float* msg_w = (const float*)d_in[15];
    const float* msg_b = (const float*)d_in[16];
    const float* upd_w = (const float*)d_in[17];
    const float* upd_b = (const float*)d_in[18];
    const float* go_w  = (const float*)d_in[19];
    const float* go_b  = (const float*)d_in[20];

    float* out = (float*)d_out;
    float* ws  = (float*)d_ws;
    float* x   = ws + X_OFF;
    float* mc  = ws + MC_OFF;

    float* h_final;
    if (ws_size >= WS_FAST_BYTES) {
        // -------- 3-dispatch fast path --------
        PrepParams pp;
        pp.alpha = alpha; pp.pos = pos;
        pp.w_in = w_in; pp.b_in = b_in;
        pp.w1a = w1a; pp.b1a = b1a; pp.w1b = w1b; pp.b1b = b1b;
        pp.w2a = w2a; pp.b2a = b2a; pp.w2b = w2b; pp.b2b = b2b;
        pp.msg_w = msg_w; pp.msg_b = msg_b; pp.upd_w = upd_w; pp.upd_b = upd_b;
        pp.x = x; pp.mc = mc;
        pp.bar = (int*)(ws + BAR_OFF);
        pp.cnt = (int*)(ws + CNT_OFF);
        pp.hA  = ws + HA_OFF;
        prep_kernel<<<1024, 256, 0, stream>>>(pp);

        GraphParams gp;
        gp.bonds = bonds; gp.mc = mc; gp.upd_b = upd_b;
        gp.cnt    = (int*)(ws + CNT_OFF);
        gp.bucket = (int*)(ws + BKT_OFF);
        gp.bar    = (int*)(ws + BAR_OFF);
        gp.hA     = ws + HA_OFF;
        gp.hB     = ws + HB_OFF;
        graph_kernel<<<GRAPH_GRID, 256, 0, stream>>>(gp);

        h_final = gp.hA;
    } else {
        // -------- fallback: multi-dispatch atomic scatter path --------
        float* degf = ws + DEGF_OFF;
        float* h_t  = ws + HT_OFF;
        size_t need_full = (size_t)(NB_OFF + N_ATOMS * 48) * sizeof(float);
        float* nb_t = (ws_size >= need_full) ? (ws + NB_OFF) : out;

        mlp_head_kernel<<<17, 256, 0, stream>>>(alpha, w_in, b_in,
                                                w1a, b1a, w1b, b1b,
                                                w2a, b2a, w2b, b2b,
                                                msg_w, msg_b, upd_w, upd_b, x, mc);
        zero4_kernel<<<(N_ATOMS / 4 + 255) / 256, 256, 0, stream>>>((int4*)degf, N_ATOMS / 4);
        degf_kernel<<<(N_BONDS + 255) / 256, 256, 0, stream>>>(bonds, degf);
        transpose_in_kernel<<<(N_ATOMS * 48 + 255) / 256, 256, 0, stream>>>(pos, h_t);
        for (int it = 0; it < 2; ++it) {
            zero4_kernel<<<(N_ATOMS * 48 / 4 + 255) / 256, 256, 0, stream>>>((int4*)nb_t, N_ATOMS * 48 / 4);
            scatter_kernel<<<25000, 192, 0, stream>>>(bonds, h_t, nb_t);
            update_kernel<<<(N_ATOMS * BATCH + 255) / 256, 256, 0, stream>>>(nb_t, degf, mc, upd_b, h_t);
        }
        h_final = h_t;
    }

    out_kernel<<<(N3 + 127) / 128, 64, 0, stream>>>(w_out, b_out, x, h_final, go_w, go_b, out);
}

// Round 7
// 127.703 us; speedup vs baseline: 6.6447x; 2.7177x over previous
//
#include <hip/hip_runtime.h>

#define N_ATOMS 50000
#define N_BONDS 100000
#define BATCH   16
#define N3      150000   // N_ATOMS*3
#define BK      32       // bucket capacity per atom (Poisson(4): P(deg>32) ~ 1e-15)

// ---- fast-path workspace layout (4-byte element offsets) ----
#define X_OFF    0            // 4096 floats
#define MC_OFF   4096         // 16 floats (M 9, c 3)
#define CNT_OFF  4112         // 50000 ints (4112*4 % 16 == 0)
#define BKT_OFF  54112        // 50000*32 = 1,600,000 ints
#define HA_OFF   1654112      // 2,400,000 floats
#define HB_OFF   4054112      // 2,400,000 floats
#define WS_FAST_BYTES ((size_t)(HB_OFF + 2400000) * 4)   // ~25.8 MB

// ---- fallback layout ----
#define DEGF_OFF 4112         // 50000 floats
#define HT_OFF   54144        // 2,400,000 floats
#define NB_OFF   2454144      // 2,400,000 floats (optional in ws)

// ================= shared device helpers =================

// tiny MLP for batch b; all 256 threads of the block participate.
__device__ __forceinline__ void mlp_block(int b, int j,
    const float* __restrict__ alpha,
    const float* __restrict__ w_in, const float* __restrict__ b_in,
    const float* __restrict__ w1a, const float* __restrict__ b1a,
    const float* __restrict__ w1b, const float* __restrict__ b1b,
    const float* __restrict__ w2a, const float* __restrict__ b2a,
    const float* __restrict__ w2b, const float* __restrict__ b2b,
    float* xs, float* ts, float* __restrict__ x_out)
{
    float v = fmaxf(w_in[j] * alpha[b] + b_in[j], 0.f);
    xs[j] = v;
    __syncthreads();

    float acc = b1a[j];
    const float4* wr = reinterpret_cast<const float4*>(w1a + j * 256);
    #pragma unroll 8
    for (int k4 = 0; k4 < 64; ++k4) {
        float4 w = wr[k4];
        acc += w.x * xs[4*k4] + w.y * xs[4*k4+1] + w.z * xs[4*k4+2] + w.w * xs[4*k4+3];
    }
    ts[j] = fmaxf(acc, 0.f);
    __syncthreads();

    acc = b1b[j] + xs[j];
    wr = reinterpret_cast<const float4*>(w1b + j * 256);
    #pragma unroll 8
    for (int k4 = 0; k4 < 64; ++k4) {
        float4 w = wr[k4];
        acc += w.x * ts[4*k4] + w.y * ts[4*k4+1] + w.z * ts[4*k4+2] + w.w * ts[4*k4+3];
    }
    v = fmaxf(acc, 0.f);
    __syncthreads();
    xs[j] = v;
    __syncthreads();

    acc = b2a[j];
    wr = reinterpret_cast<const float4*>(w2a + j * 256);
    #pragma unroll 8
    for (int k4 = 0; k4 < 64; ++k4) {
        float4 w = wr[k4];
        acc += w.x * xs[4*k4] + w.y * xs[4*k4+1] + w.z * xs[4*k4+2] + w.w * xs[4*k4+3];
    }
    ts[j] = fmaxf(acc, 0.f);
    __syncthreads();

    acc = b2b[j] + xs[j];
    wr = reinterpret_cast<const float4*>(w2b + j * 256);
    #pragma unroll 8
    for (int k4 = 0; k4 < 64; ++k4) {
        float4 w = wr[k4];
        acc += w.x * ts[4*k4] + w.y * ts[4*k4+1] + w.z * ts[4*k4+2] + w.w * ts[4*k4+3];
    }
    x_out[b * 256 + j] = fmaxf(acc, 0.f);
}

// ================= K1: prep (MLP + mc + transpose + cnt-zero) =================
struct PrepParams {
    const float *alpha, *pos;
    const float *w_in, *b_in, *w1a, *b1a, *w1b, *b1b, *w2a, *b2a, *w2b, *b2b;
    const float *msg_w, *msg_b, *upd_w, *upd_b;
    float *x, *mc;
    int *cnt;
    float *hA;
};

__global__ __launch_bounds__(256) void prep_kernel(PrepParams p)
{
    __shared__ float smem[512];
    const int bid = blockIdx.x, tid = threadIdx.x;
    const int nb = gridDim.x;

    if (bid < 16) {
        mlp_block(bid, tid, p.alpha, p.w_in, p.b_in,
                  p.w1a, p.b1a, p.w1b, p.b1b, p.w2a, p.b2a, p.w2b, p.b2b,
                  smem, smem + 256, p.x);
    } else if (bid == 16) {
        if (tid < 9) {
            int d = tid / 3, dp = tid % 3;
            float s = 0.f;
            for (int k = 0; k < 128; ++k) s += p.upd_w[d*128 + k] * p.msg_w[k*3 + dp];
            p.mc[tid] = s;
        } else if (tid < 12) {
            int d = tid - 9;
            float s = p.upd_b[d];
            for (int k = 0; k < 128; ++k) s += p.upd_w[d*128 + k] * p.msg_b[k];
            p.mc[9 + d] = s;
        }
    } else {
        const int i0 = (bid - 17) * 256 + tid;
        const int st = (nb - 17) * 256;
        if (i0 < N_ATOMS / 4)
            ((int4*)p.cnt)[i0] = make_int4(0, 0, 0, 0);
        for (int i = i0; i < N_ATOMS * 48; i += st) {
            int n = i / 48, c = i - n * 48;
            int b = c / 3, d = c - b * 3;
            p.hA[i] = p.pos[(b * N_ATOMS + n) * 3 + d];
        }
    }
}

// ================= K2: bucket fill (count + adjacency in one pass) =================
__global__ void fill_kernel(const int* __restrict__ bonds, int* __restrict__ cnt,
                            int* __restrict__ bucket)
{
    int e = blockIdx.x * blockDim.x + threadIdx.x;
    if (e >= N_BONDS) return;
    int a = bonds[2*e], b = bonds[2*e + 1];
    int sa = atomicAdd(cnt + a, 1);
    if (sa < BK) bucket[a * BK + sa] = b;
    int sb = atomicAdd(cnt + b, 1);
    if (sb < BK) bucket[b * BK + sb] = a;
}

// ============ K3/K4: bucket gather + mean + affine + residual ============
// h_out = h_in + M*mean_nb(h_in) + c ; 16 lanes per atom (b = lane&15) give
// 192B-contiguous access groups on the transposed h layout.
__global__ void gather_kernel(const int* __restrict__ cnt, const int* __restrict__ bucket,
                              const float* __restrict__ mc, const float* __restrict__ upd_b,
                              const float* __restrict__ h_in, float* __restrict__ h_out)
{
    int t = blockIdx.x * blockDim.x + threadIdx.x;
    if (t >= N_ATOMS * BATCH) return;
    int n = t >> 4, b = t & 15;
    int dg = cnt[n];
    int base = n * 48 + b * 3;
    float d0, d1, d2;
    if (dg > 0) {
        int m = dg > BK ? BK : dg;
        float s0 = 0.f, s1 = 0.f, s2 = 0.f;
        const int* bk = bucket + n * BK;
        for (int j = 0; j < m; ++j) {
            const float* hs = h_in + bk[j] * 48 + b * 3;
            s0 += hs[0]; s1 += hs[1]; s2 += hs[2];
        }
        float inv = 1.f / (float)dg;
        s0 *= inv; s1 *= inv; s2 *= inv;
        d0 = mc[9]  + mc[0]*s0 + mc[1]*s1 + mc[2]*s2;
        d1 = mc[10] + mc[3]*s0 + mc[4]*s1 + mc[5]*s2;
        d2 = mc[11] + mc[6]*s0 + mc[7]*s1 + mc[8]*s2;
    } else {
        d0 = upd_b[0]; d1 = upd_b[1]; d2 = upd_b[2];
    }
    h_out[base]     = h_in[base]     + d0;
    h_out[base + 1] = h_in[base + 1] + d1;
    h_out[base + 2] = h_in[base + 2] + d2;
}

// ---------------- K5: fused output GEMM + b_out + go-affine(h) ----------------
__global__ __launch_bounds__(64) void out_kernel(
    const float* __restrict__ w_out, const float* __restrict__ b_out,
    const float* __restrict__ x, const float* __restrict__ h_t,
    const float* __restrict__ go_w, const float* __restrict__ go_b,
    float* __restrict__ out)
{
    __shared__ float4 xs[1024];                 // [b][k4], 16 KiB
    const int tid = threadIdx.x;
    const float4* xv = reinterpret_cast<const float4*>(x);
    #pragma unroll
    for (int i = 0; i < 16; ++i) xs[tid + i * 64] = xv[tid + i * 64];
    __syncthreads();

    const int r0 = blockIdx.x * 128 + tid;
    const int r1 = r0 + 64;
    const bool v1 = (r1 < N3);
    const int r1c = v1 ? r1 : r0;

    const float4* wr0 = reinterpret_cast<const float4*>(w_out + (size_t)r0 * 256);
    const float4* wr1 = reinterpret_cast<const float4*>(w_out + (size_t)r1c * 256);

    float acc0[16], acc1[16];
    #pragma unroll
    for (int b = 0; b < 16; ++b) { acc0[b] = 0.f; acc1[b] = 0.f; }

    float4 wbuf0[4], wbuf1[4];
    #pragma unroll
    for (int i = 0; i < 4; ++i) { wbuf0[i] = wr0[i]; wbuf1[i] = wr1[i]; }

    #pragma unroll 1
    for (int c = 0; c < 16; ++c) {
        float4 wc0[4], wc1[4];
        #pragma unroll
        for (int i = 0; i < 4; ++i) { wc0[i] = wbuf0[i]; wc1[i] = wbuf1[i]; }
        if (c < 15) {
            #pragma unroll
            for (int i = 0; i < 4; ++i) {
                wbuf0[i] = wr0[(c + 1) * 4 + i];
                wbuf1[i] = wr1[(c + 1) * 4 + i];
            }
        }
        #pragma unroll
        for (int i = 0; i < 4; ++i) {
            const int k4 = c * 4 + i;
            #pragma unroll
            for (int b = 0; b < 16; ++b) {
                float4 xf = xs[b * 64 + k4];
                acc0[b] += wc0[i].x * xf.x + wc0[i].y * xf.y
                         + wc0[i].z * xf.z + wc0[i].w * xf.w;
                acc1[b] += wc1[i].x * xf.x + wc1[i].y * xf.y
                         + wc1[i].z * xf.z + wc1[i].w * xf.w;
            }
        }
    }

    {
        const int n = r0 / 3, d = r0 - 3 * n;
        const float g0 = go_w[d*3], g1 = go_w[d*3 + 1], g2 = go_w[d*3 + 2];
        const float gb = go_b[d] + b_out[r0];
        const float* hb = h_t + n * 48;
        #pragma unroll
        for (int b = 0; b < 16; ++b) {
            float g = gb + g0 * hb[b*3] + g1 * hb[b*3 + 1] + g2 * hb[b*3 + 2];
            out[b * N3 + r0] = acc0[b] + g;
        }
    }
    if (v1) {
        const int n = r1 / 3, d = r1 - 3 * n;
        const float g0 = go_w[d*3], g1 = go_w[d*3 + 1], g2 = go_w[d*3 + 2];
        const float gb = go_b[d] + b_out[r1];
        const float* hb = h_t + n * 48;
        #pragma unroll
        for (int b = 0; b < 16; ++b) {
            float g = gb + g0 * hb[b*3] + g1 * hb[b*3 + 1] + g2 * hb[b*3 + 2];
            out[b * N3 + r1] = acc1[b] + g;
        }
    }
}

// ================= fallback (small-ws) kernels: atomic scatter path =================
__global__ void zero4_kernel(int4* __restrict__ p, int n4)
{
    int t = blockIdx.x * 256 + threadIdx.x;
    if (t < n4) p[t] = make_int4(0, 0, 0, 0);
}

__global__ void mlp_head_kernel(const float* __restrict__ alpha,
    const float* __restrict__ w_in, const float* __restrict__ b_in,
    const float* __restrict__ w1a, const float* __restrict__ b1a,
    const float* __restrict__ w1b, const float* __restrict__ b1b,
    const float* __restrict__ w2a, const float* __restrict__ b2a,
    const float* __restrict__ w2b, const float* __restrict__ b2b,
    const float* __restrict__ msg_w, const float* __restrict__ msg_b,
    const float* __restrict__ upd_w, const float* __restrict__ upd_b,
    float* __restrict__ x_out, float* __restrict__ mc)
{
    const int b = blockIdx.x, j = threadIdx.x;
    if (b == 16) {
        if (j < 9) {
            int d = j / 3, dp = j % 3;
            float s = 0.f;
            for (int k = 0; k < 128; ++k) s += upd_w[d*128 + k] * msg_w[k*3 + dp];
            mc[j] = s;
        } else if (j < 12) {
            int d = j - 9;
            float s = upd_b[d];
            for (int k = 0; k < 128; ++k) s += upd_w[d*128 + k] * msg_b[k];
            mc[9 + d] = s;
        }
        return;
    }
    __shared__ float xs[256];
    __shared__ float ts[256];
    mlp_block(b, j, alpha, w_in, b_in, w1a, b1a, w1b, b1b, w2a, b2a, w2b, b2b,
              xs, ts, x_out);
}

__global__ void transpose_in_kernel(const float* __restrict__ pos, float* __restrict__ h_t)
{
    int t = blockIdx.x * blockDim.x + threadIdx.x;
    if (t >= N_ATOMS * 48) return;
    int n = t / 48, c = t % 48;
    int b = c / 3, d = c % 3;
    h_t[t] = pos[(b * N_ATOMS + n) * 3 + d];
}

__global__ void degf_kernel(const int* __restrict__ bonds, float* __restrict__ deg)
{
    int e = blockIdx.x * blockDim.x + threadIdx.x;
    if (e >= N_BONDS) return;
    atomicAdd(deg + bonds[2*e],     1.f);
    atomicAdd(deg + bonds[2*e + 1], 1.f);
}

__global__ void scatter_kernel(const int* __restrict__ bonds,
                               const float* __restrict__ h_t, float* __restrict__ nb_t)
{
    int t = blockIdx.x * 192 + threadIdx.x;
    int e = t / 48, c = t % 48;
    if (e >= N_BONDS) return;
    int a  = bonds[2*e];
    int bb = bonds[2*e + 1];
    float va = h_t[a  * 48 + c];
    float vb = h_t[bb * 48 + c];
    atomicAdd(nb_t + bb * 48 + c, va);
    atomicAdd(nb_t + a  * 48 + c, vb);
}

__global__ void update_kernel(const float* __restrict__ nb_t, const float* __restrict__ deg,
                              const float* __restrict__ mc, const float* __restrict__ upd_b,
                              float* __restrict__ h_t)
{
    int t = blockIdx.x * blockDim.x + threadIdx.x;
    if (t >= N_ATOMS * BATCH) return;
    int n = t >> 4;
    int base = n * 48 + (t & 15) * 3;
    float dg = deg[n];
    float d0, d1, d2;
    if (dg > 0.f) {
        float inv = 1.f / dg;
        float m0 = nb_t[base] * inv, m1 = nb_t[base+1] * inv, m2 = nb_t[base+2] * inv;
        d0 = mc[9]  + mc[0]*m0 + mc[1]*m1 + mc[2]*m2;
        d1 = mc[10] + mc[3]*m0 + mc[4]*m1 + mc[5]*m2;
        d2 = mc[11] + mc[6]*m0 + mc[7]*m1 + mc[8]*m2;
    } else {
        d0 = upd_b[0]; d1 = upd_b[1]; d2 = upd_b[2];
    }
    h_t[base]     += d0;
    h_t[base + 1] += d1;
    h_t[base + 2] += d2;
}

extern "C" void kernel_launch(void* const* d_in, const int* in_sizes, int n_in,
                              void* d_out, int out_size, void* d_ws, size_t ws_size,
                              hipStream_t stream)
{
    const float* alpha = (const float*)d_in[0];
    const float* pos   = (const float*)d_in[1];
    const int*   bonds = (const int*)  d_in[2];
    const float* w_in  = (const float*)d_in[3];
    const float* b_in  = (const float*)d_in[4];
    const float* w1a   = (const float*)d_in[5];
    const float* b1a   = (const float*)d_in[6];
    const float* w1b   = (const float*)d_in[7];
    const float* b1b   = (const float*)d_in[8];
    const float* w2a   = (const float*)d_in[9];
    const float* b2a   = (const float*)d_in[10];
    const float* w2b   = (const float*)d_in[11];
    const float* b2b   = (const float*)d_in[12];
    const float* w_out = (const float*)d_in[13];
    const float* b_out = (const float*)d_in[14];
    const float* msg_w = (const float*)d_in[15];
    const float* msg_b = (const float*)d_in[16];
    const float* upd_w = (const float*)d_in[17];
    const float* upd_b = (const float*)d_in[18];
    const float* go_w  = (const float*)d_in[19];
    const float* go_b  = (const float*)d_in[20];

    float* out = (float*)d_out;
    float* ws  = (float*)d_ws;
    float* x   = ws + X_OFF;
    float* mc  = ws + MC_OFF;

    float* h_final;
    if (ws_size >= WS_FAST_BYTES) {
        // -------- 5-dispatch full-occupancy fast path --------
        PrepParams pp;
        pp.alpha = alpha; pp.pos = pos;
        pp.w_in = w_in; pp.b_in = b_in;
        pp.w1a = w1a; pp.b1a = b1a; pp.w1b = w1b; pp.b1b = b1b;
        pp.w2a = w2a; pp.b2a = b2a; pp.w2b = w2b; pp.b2b = b2b;
        pp.msg_w = msg_w; pp.msg_b = msg_b; pp.upd_w = upd_w; pp.upd_b = upd_b;
        pp.x = x; pp.mc = mc;
        pp.cnt = (int*)(ws + CNT_OFF);
        pp.hA  = ws + HA_OFF;
        prep_kernel<<<1024, 256, 0, stream>>>(pp);

        int* cnt    = (int*)(ws + CNT_OFF);
        int* bucket = (int*)(ws + BKT_OFF);
        float* hA   = ws + HA_OFF;
        float* hB   = ws + HB_OFF;

        fill_kernel<<<(N_BONDS + 255) / 256, 256, 0, stream>>>(bonds, cnt, bucket);
        gather_kernel<<<(N_ATOMS * BATCH + 255) / 256, 256, 0, stream>>>(cnt, bucket, mc, upd_b, hA, hB);
        gather_kernel<<<(N_ATOMS * BATCH + 255) / 256, 256, 0, stream>>>(cnt, bucket, mc, upd_b, hB, hA);
        h_final = hA;
    } else {
        // -------- fallback: multi-dispatch atomic scatter path --------
        float* degf = ws + DEGF_OFF;
        float* h_t  = ws + HT_OFF;
        size_t need_full = (size_t)(NB_OFF + N_ATOMS * 48) * sizeof(float);
        float* nb_t = (ws_size >= need_full) ? (ws + NB_OFF) : out;

        mlp_head_kernel<<<17, 256, 0, stream>>>(alpha, w_in, b_in,
                                                w1a, b1a, w1b, b1b,
                                                w2a, b2a, w2b, b2b,
                                                msg_w, msg_b, upd_w, upd_b, x, mc);
        zero4_kernel<<<(N_ATOMS / 4 + 255) / 256, 256, 0, stream>>>((int4*)degf, N_ATOMS / 4);
        degf_kernel<<<(N_BONDS + 255) / 256, 256, 0, stream>>>(bonds, degf);
        transpose_in_kernel<<<(N_ATOMS * 48 + 255) / 256, 256, 0, stream>>>(pos, h_t);
        for (int it = 0; it < 2; ++it) {
            zero4_kernel<<<(N_ATOMS * 48 / 4 + 255) / 256, 256, 0, stream>>>((int4*)nb_t, N_ATOMS * 48 / 4);
            scatter_kernel<<<25000, 192, 0, stream>>>(bonds, h_t, nb_t);
            update_kernel<<<(N_ATOMS * BATCH + 255) / 256, 256, 0, stream>>>(nb_t, degf, mc, upd_b, h_t);
        }
        h_final = h_t;
    }

    out_kernel<<<(N3 + 127) / 128, 64, 0, stream>>>(w_out, b_out, x, h_final, go_w, go_b, out);
}